// Round 3
// baseline (11251.799 us; speedup 1.0000x reference)
//
#include <hip/hip_runtime.h>
#include <hip/hip_bf16.h>
#include <hip/hip_cooperative_groups.h>
#include <math.h>

namespace cg = cooperative_groups;

// Problem constants
#define NN      1500
#define NEE     1200
#define NPAD    1536
#define BATCH   96
#define NSTEP   60
#define NIT     16            // i tiles (96 each)
#define NKT     16            // k tiles (96 each)
#define TS      96            // tile size in i and k
#define PADK    104           // padded k stride in LDS (2-way banks, free)
#define SLAB    (TS*PADK)     // 9984 ushorts per plane
#define NWG     (NIT*NKT)     // 256 workgroups (1 per CU)
#define NTHR    384           // 6 waves
#define TOT     (BATCH*NPAD)  // 147456 update elements
#define SMEM_BYTES (6*SLAB*2) // 119808 B: Whi,Wlo,W2hi,W2lo,Ahi,Alo
#define PI_F    3.14159265358979323846f

typedef __attribute__((ext_vector_type(8))) short short8b;  // 8 bf16
typedef __attribute__((ext_vector_type(4))) float f32x4;    // MFMA acc

// ---------------- bf16 split helpers ----------------------------------------

__device__ __forceinline__ ushort bf16_rn(float x) {
    unsigned u = __float_as_uint(x);
    unsigned r = (u + 0x7FFFu + ((u >> 16) & 1u)) >> 16;
    return (ushort)r;
}
__device__ __forceinline__ float bf16f(ushort h) {
    return __uint_as_float(((unsigned)h) << 16);
}

// ---------------- phi (Ricciardi LIF transfer) ------------------------------

__device__ __forceinline__ float f_ricci(float x) {
    float z = x / (1.0f + x);
    float t = -z;
    float p = 0.14805913578876898f;
    p = p * t + 0.64290613877355551f;
    p = p * t + 1.0616084849547165f;
    p = p * t + 0.93524391761244940f;
    p = p * t + 0.62718906618071668f;
    p = p * t + 0.32171431660633076f;
    p = p * t + 0.32056016125642045f;
    p = p * t + 0.77373949685442023f;
    p = p * t + 0.22757881388024176f;
    p = p * t;
    return logf(2.0f * x + 1.0f) + p;
}

__device__ __forceinline__ float g_ricci(float x) {
    float z = x / (2.0f + x);
    float num = z * (3.5441754117462949f + z * (-7.0529131065835378f + z * (-56.532378057580381f
        + z * (279.56761105465944f + z * (-520.37554849441472f + z * (456.58245777026514f
        + z * (-155.73340457809226f)))))));
    float den = 1.0f + z * (-4.1357968834226053f + z * (-7.2984226138266743f + z * (98.656602235468327f
        + z * (-334.20436223415163f + z * (601.08633903294185f + z * (-599.58577549598340f
        + z * (277.18420330693891f + z * (-16.445022798669722f))))))));
    return num / den;
}

__device__ __forceinline__ float phi_lif(float mu, float sig, float tau, float tau_ref) {
    float xp = mu / sig;
    float xm = (mu - 20.0f) / sig;
    float r0;
    if (xm > 0.0f) {
        r0 = 1.0f / (f_ricci(xp) - f_ricci(xm));
    } else if (xp > 0.0f) {
        r0 = 1.0f / (f_ricci(xp) + expf(xm * xm) * g_ricci(-xm));
    } else {
        float a = g_ricci(-xm) - expf(xp * xp - xm * xm) * g_ricci(-xp);
        r0 = expf(-xm * xm - logf(a));
    }
    r0 = fmaxf(r0, 1e-30f);
    return 1.0f / (tau_ref + tau / r0);
}

__device__ __forceinline__ float pref_of(int n) {
    const float stepE = 179.99f / 1200.0f;
    const float stepI = 179.99f / 300.0f;
    return (n < NEE) ? (float)n * stepE : (float)(n - NEE) * stepI;
}

// ---------------- single persistent cooperative kernel ----------------------
// WG (it,kt) owns W[i in it*96..+96][k in kt*96..+96], kept in LDS as 4 bf16
// split planes. Per step: stage rate slab (LDS) -> MFMA partials -> grid.sync
// -> per-thread reduce+phi+update (rate in registers) -> grid.sync.

__global__ __launch_bounds__(NTHR) void k_coop(
        const float* __restrict__ hyp, const float* __restrict__ rand_mat,
        ushort* __restrict__ rhi, ushort* __restrict__ rlo,
        float* __restrict__ part1, float* __restrict__ part2,
        float* __restrict__ out)
{
    cg::grid_group grid = cg::this_grid();
    extern __shared__ ushort sm[];
    ushort* sWhi  = sm;
    ushort* sWlo  = sm + SLAB;
    ushort* sW2hi = sm + 2 * SLAB;
    ushort* sW2lo = sm + 3 * SLAB;
    ushort* sAhi  = sm + 4 * SLAB;
    ushort* sAlo  = sm + 5 * SLAB;

    const int wg  = blockIdx.x;
    const int tid = threadIdx.x;
    const int it  = wg & (NIT - 1);
    const int kt  = wg >> 4;

    // ---- build weight slice into LDS (once) ----
    for (int e = tid; e < TS * TS; e += NTHR) {
        const int li = e / TS;
        const int lk = e - li * TS;
        const int ig = it * TS + li;
        const int kg = kt * TS + lk;
        float w = 0.0f;
        if (ig < NN && kg < NN) {
            float diff = fabsf(pref_of(ig) - pref_of(kg));
            int conn = (ig >= NEE ? 1 : 0) + 2 * (kg >= NEE ? 1 : 0);
            float J = hyp[conn], P = hyp[4 + conn], Wp = hyp[8 + conn];
            float dn = 4.0f * (PI_F / 180.0f * Wp) * (PI_F / 180.0f * Wp);
            float z = expf((cosf(2.0f * PI_F / 180.0f * diff) - 1.0f) / dn);
            float x = 32.0f * (P * z - rand_mat[(size_t)ig * NN + kg]);
            w = J / (1.0f + expf(-x));
        }
        float w2 = w * w;
        int o = li * PADK + lk;
        ushort h = bf16_rn(w);
        sWhi[o] = h;  sWlo[o] = bf16_rn(w - bf16f(h));
        ushort h2 = bf16_rn(w2);
        sW2hi[o] = h2; sW2lo[o] = bf16_rn(w2 - bf16f(h2));
    }

    // ---- per-thread update-element state (rate lives in registers) ----
    const int e0 = wg * NTHR + tid;          // always < TOT
    const int e1 = e0 + NWG * NTHR;          // may be >= TOT
    const int b0 = e0 / NPAD, i0 = e0 - b0 * NPAD;
    const bool has1 = (e1 < TOT);
    const int b1 = has1 ? e1 / NPAD : 0;
    const int i1 = has1 ? (e1 - (e1 / NPAD) * NPAD) : 0;

    const float contrasts[8] = {0.0f, 0.0432773f, 0.103411f, 0.186966f,
                                0.303066f, 0.464386f, 0.68854f, 1.0f};
    const float dnff = 4.0f * (PI_F / 180.0f * 30.0f) * (PI_F / 180.0f * 30.0f);
    float mean0 = 0.0f, mean1 = 0.0f;
    if (i0 < NN) {
        int c = b0 / 12, oo = b0 - (b0 / 12) * 12;
        float dth = 15.0f * (float)oo - pref_of(i0);
        mean0 = contrasts[c] * 20.0f * expf((cosf(2.0f * PI_F / 180.0f * dth) - 1.0f) / dnff);
    }
    if (has1 && i1 < NN) {
        int c = b1 / 12, oo = b1 - (b1 / 12) * 12;
        float dth = 15.0f * (float)oo - pref_of(i1);
        mean1 = contrasts[c] * 20.0f * expf((cosf(2.0f * PI_F / 180.0f * dth) - 1.0f) / dnff);
    }
    float r0 = 0.0f, r1 = 0.0f;

    // zero-init bf16 rate planes (pad rows stay zero forever)
    rhi[e0] = 0; rlo[e0] = 0;
    if (has1) { rhi[e1] = 0; rlo[e1] = 0; }

    grid.sync();

    // ---- GEMM lane constants ----
    const int wave = tid >> 6;
    const int lane = tid & 63;
    const int lr = lane & 15;
    const int lq = lane >> 4;
    const int bb = (wave * 16 + lr) * PADK + lq * 8;   // B-frag base (ushort idx)
    const int icg = it * TS + wave * 16 + lr;          // global i of C column

    for (int s = 0; s < NSTEP; s++) {
        // stage A slab: rate bf16 hi/lo for k in [kt*96, kt*96+96), all 96 b
        for (int c = tid; c < TS * 12; c += NTHR) {
            int b = c / 12;
            int ko = (c - b * 12) * 8;
            size_t g = (size_t)b * NPAD + kt * TS + ko;
            *(short8b*)(sAhi + b * PADK + ko) = *(const short8b*)(rhi + g);
            *(short8b*)(sAlo + b * PADK + ko) = *(const short8b*)(rlo + g);
        }
        __syncthreads();

        f32x4 acc1[6], acc2[6];
#pragma unroll
        for (int m = 0; m < 6; m++) {
            acc1[m] = (f32x4){0.0f, 0.0f, 0.0f, 0.0f};
            acc2[m] = (f32x4){0.0f, 0.0f, 0.0f, 0.0f};
        }

#pragma unroll
        for (int kk = 0; kk < 3; kk++) {
            short8b bh  = *(const short8b*)(sWhi  + bb + kk * 32);
            short8b bl  = *(const short8b*)(sWlo  + bb + kk * 32);
            short8b b2h = *(const short8b*)(sW2hi + bb + kk * 32);
            short8b b2l = *(const short8b*)(sW2lo + bb + kk * 32);
#pragma unroll
            for (int m = 0; m < 6; m++) {
                const int ab = (m * 16 + lr) * PADK + lq * 8 + kk * 32;
                short8b ah = *(const short8b*)(sAhi + ab);
                short8b al = *(const short8b*)(sAlo + ab);
                acc1[m] = __builtin_amdgcn_mfma_f32_16x16x32_bf16(ah, bh,  acc1[m], 0, 0, 0);
                acc1[m] = __builtin_amdgcn_mfma_f32_16x16x32_bf16(ah, bl,  acc1[m], 0, 0, 0);
                acc1[m] = __builtin_amdgcn_mfma_f32_16x16x32_bf16(al, bh,  acc1[m], 0, 0, 0);
                acc1[m] = __builtin_amdgcn_mfma_f32_16x16x32_bf16(al, bl,  acc1[m], 0, 0, 0);
                acc2[m] = __builtin_amdgcn_mfma_f32_16x16x32_bf16(ah, b2h, acc2[m], 0, 0, 0);
                acc2[m] = __builtin_amdgcn_mfma_f32_16x16x32_bf16(ah, b2l, acc2[m], 0, 0, 0);
                acc2[m] = __builtin_amdgcn_mfma_f32_16x16x32_bf16(al, b2h, acc2[m], 0, 0, 0);
                acc2[m] = __builtin_amdgcn_mfma_f32_16x16x32_bf16(al, b2l, acc2[m], 0, 0, 0);
            }
        }

        // write partials: C/D layout col=lane&15 (i), row=(lane>>4)*4+r (b)
#pragma unroll
        for (int m = 0; m < 6; m++) {
#pragma unroll
            for (int r = 0; r < 4; r++) {
                int b = m * 16 + lq * 4 + r;
                size_t o = (size_t)(kt * BATCH + b) * NPAD + icg;
                part1[o] = acc1[m][r];
                part2[o] = acc2[m][r];
            }
        }
        __threadfence();
        grid.sync();

        // ---- update phase: reduce 16 partials + phi + Euler (regs) ----
        if (i0 < NN) {
            float u1 = 0.0f, u2 = 0.0f;
#pragma unroll
            for (int ks = 0; ks < NKT; ks++) {
                size_t o = (size_t)(ks * BATCH + b0) * NPAD + i0;
                u1 += part1[o]; u2 += part2[o];
            }
            float mu = 0.01f * u1 + mean0;
            float sg = sqrtf(0.01f * u2 + 25.0f);
            float tr = (i0 < NEE) ? 0.005f : 0.001f;
            float Ti = (i0 < NEE) ? 100.0f : 200.0f;
            float ph = phi_lif(mu, sg, 0.01f, tr);
            r0 = r0 + 1e-3f * Ti * (ph - r0);
            ushort h = bf16_rn(r0);
            rhi[e0] = h; rlo[e0] = bf16_rn(r0 - bf16f(h));
        }
        if (has1 && i1 < NN) {
            float u1 = 0.0f, u2 = 0.0f;
#pragma unroll
            for (int ks = 0; ks < NKT; ks++) {
                size_t o = (size_t)(ks * BATCH + b1) * NPAD + i1;
                u1 += part1[o]; u2 += part2[o];
            }
            float mu = 0.01f * u1 + mean1;
            float sg = sqrtf(0.01f * u2 + 25.0f);
            float tr = (i1 < NEE) ? 0.005f : 0.001f;
            float Ti = (i1 < NEE) ? 100.0f : 200.0f;
            float ph = phi_lif(mu, sg, 0.01f, tr);
            r1 = r1 + 1e-3f * Ti * (ph - r1);
            ushort h = bf16_rn(r1);
            rhi[e1] = h; rlo[e1] = bf16_rn(r1 - bf16f(h));
        }
        __threadfence();
        grid.sync();
    }

    // ---- final output: out[i][c][o] = out[i*96 + b] ----
    if (i0 < NN) out[(size_t)i0 * BATCH + b0] = r0;
    if (has1 && i1 < NN) out[(size_t)i1 * BATCH + b1] = r1;
}

// ---------------- launch ----------------------------------------------------

extern "C" void kernel_launch(void* const* d_in, const int* in_sizes, int n_in,
                              void* d_out, int out_size, void* d_ws, size_t ws_size,
                              hipStream_t stream) {
    const float* hyp      = (const float*)d_in[0];   // [3][4]
    const float* rand_mat = (const float*)d_in[1];   // [1500][1500]
    float* out            = (float*)d_out;           // [1500][8][12]

    char* p = (char*)d_ws;
    float*  part1 = (float*)p;  p += (size_t)NKT * BATCH * NPAD * 4;
    float*  part2 = (float*)p;  p += (size_t)NKT * BATCH * NPAD * 4;
    ushort* rhi   = (ushort*)p; p += (size_t)BATCH * NPAD * 2;
    ushort* rlo   = (ushort*)p; p += (size_t)BATCH * NPAD * 2;

    hipFuncSetAttribute((const void*)k_coop,
                        hipFuncAttributeMaxDynamicSharedMemorySize, SMEM_BYTES);

    void* args[] = {(void*)&hyp, (void*)&rand_mat, (void*)&rhi, (void*)&rlo,
                    (void*)&part1, (void*)&part2, (void*)&out};
    hipLaunchCooperativeKernel((const void*)k_coop, dim3(NWG), dim3(NTHR),
                               args, SMEM_BYTES, stream);
}

// Round 4
// 1727.290 us; speedup vs baseline: 6.5141x; 6.5141x over previous
//
#include <hip/hip_runtime.h>
#include <hip/hip_bf16.h>
#include <math.h>

// Problem constants
#define NN      1500
#define NEE     1200
#define NPAD    1536
#define BATCH   96
#define NSTEP   60
#define NTHR    1024          // 16 waves per WG
#define KSL     96            // k-slice per wave (16 waves x 96 = 1536)
#define PI_F    3.14159265358979323846f

// LDS reduction buffer: 8 slots x [2 outputs][16 i][100 b-padded] f32
#define BPAD    100
#define SLOTF   (2 * 16 * BPAD)          // 3200 floats per slot
#define NSLOT   8
#define SMEM_BYTES (NSLOT * SLOTF * 4)   // 102400 B

typedef __attribute__((ext_vector_type(8))) short short8b;  // 8 bf16
typedef __attribute__((ext_vector_type(4))) float f32x4;    // MFMA acc

// ---------------- bf16 split helpers ----------------------------------------

__device__ __forceinline__ ushort bf16_rn(float x) {
    unsigned u = __float_as_uint(x);
    unsigned r = (u + 0x7FFFu + ((u >> 16) & 1u)) >> 16;
    return (ushort)r;
}
__device__ __forceinline__ float bf16f(ushort h) {
    return __uint_as_float(((unsigned)h) << 16);
}

// ---------------- phi (Ricciardi LIF transfer) ------------------------------

__device__ __forceinline__ float f_ricci(float x) {
    float z = x / (1.0f + x);
    float t = -z;
    float p = 0.14805913578876898f;
    p = p * t + 0.64290613877355551f;
    p = p * t + 1.0616084849547165f;
    p = p * t + 0.93524391761244940f;
    p = p * t + 0.62718906618071668f;
    p = p * t + 0.32171431660633076f;
    p = p * t + 0.32056016125642045f;
    p = p * t + 0.77373949685442023f;
    p = p * t + 0.22757881388024176f;
    p = p * t;
    return logf(2.0f * x + 1.0f) + p;
}

__device__ __forceinline__ float g_ricci(float x) {
    float z = x / (2.0f + x);
    float num = z * (3.5441754117462949f + z * (-7.0529131065835378f + z * (-56.532378057580381f
        + z * (279.56761105465944f + z * (-520.37554849441472f + z * (456.58245777026514f
        + z * (-155.73340457809226f)))))));
    float den = 1.0f + z * (-4.1357968834226053f + z * (-7.2984226138266743f + z * (98.656602235468327f
        + z * (-334.20436223415163f + z * (601.08633903294185f + z * (-599.58577549598340f
        + z * (277.18420330693891f + z * (-16.445022798669722f))))))));
    return num / den;
}

__device__ __forceinline__ float phi_lif(float mu, float sig, float tau, float tau_ref) {
    float xp = mu / sig;
    float xm = (mu - 20.0f) / sig;
    float r0;
    if (xm > 0.0f) {
        r0 = 1.0f / (f_ricci(xp) - f_ricci(xm));
    } else if (xp > 0.0f) {
        r0 = 1.0f / (f_ricci(xp) + expf(xm * xm) * g_ricci(-xm));
    } else {
        float a = g_ricci(-xm) - expf(xp * xp - xm * xm) * g_ricci(-xp);
        r0 = expf(-xm * xm - logf(a));
    }
    r0 = fmaxf(r0, 1e-30f);
    return 1.0f / (tau_ref + tau / r0);
}

__device__ __forceinline__ float pref_of(int n) {
    const float stepE = 179.99f / 1200.0f;
    const float stepI = 179.99f / 300.0f;
    return (n < NEE) ? (float)n * stepE : (float)(n - NEE) * stepI;
}

// ---------------- kernel 1: build bf16-split weight planes [i][k] -----------

__global__ __launch_bounds__(256) void k_weights(const float* __restrict__ hyp,
        const float* __restrict__ rand_mat,
        ushort* __restrict__ Whi, ushort* __restrict__ Wlo,
        ushort* __restrict__ W2hi, ushort* __restrict__ W2lo) {
    int k = blockIdx.x * 256 + threadIdx.x;   // source neuron (contiguous)
    int i = blockIdx.y;                        // dest neuron
    size_t idx = (size_t)i * NPAD + k;
    if (i >= NN || k >= NN) {
        Whi[idx] = 0; Wlo[idx] = 0; W2hi[idx] = 0; W2lo[idx] = 0;
        return;
    }
    float diff = fabsf(pref_of(i) - pref_of(k));
    int conn = (i >= NEE ? 1 : 0) + 2 * (k >= NEE ? 1 : 0);
    float J  = hyp[conn];
    float P  = hyp[4 + conn];
    float Wp = hyp[8 + conn];
    float dn = 4.0f * (PI_F / 180.0f * Wp) * (PI_F / 180.0f * Wp);
    float z = expf((cosf(2.0f * PI_F / 180.0f * diff) - 1.0f) / dn);
    float x = 32.0f * (P * z - rand_mat[(size_t)i * NN + k]);
    float w = J / (1.0f + expf(-x));
    float w2 = w * w;
    ushort h = bf16_rn(w);
    Whi[idx] = h;  Wlo[idx] = bf16_rn(w - bf16f(h));
    ushort h2 = bf16_rn(w2);
    W2hi[idx] = h2; W2lo[idx] = bf16_rn(w2 - bf16f(h2));
}

// ---------------- kernel 2: mean + zero-init rate state ---------------------

__global__ __launch_bounds__(256) void k_init(float* __restrict__ mean,
                                              float* __restrict__ rate,
                                              ushort* __restrict__ rhiA,
                                              ushort* __restrict__ rloA) {
    int i = blockIdx.x * 256 + threadIdx.x;
    int b = blockIdx.y;                        // batch = c*12 + o
    int c = b / 12, o = b % 12;
    const float contrasts[8] = {0.0f, 0.0432773f, 0.103411f, 0.186966f,
                                0.303066f, 0.464386f, 0.68854f, 1.0f};
    float m = 0.0f;
    if (i < NN) {
        float dth = 15.0f * (float)o - pref_of(i);
        const float dn = 4.0f * (PI_F / 180.0f * 30.0f) * (PI_F / 180.0f * 30.0f);
        m = contrasts[c] * 20.0f * expf((cosf(2.0f * PI_F / 180.0f * dth) - 1.0f) / dn);
    }
    size_t idx = (size_t)b * NPAD + i;
    mean[idx] = m;
    rate[idx] = 0.0f;
    rhiA[idx] = 0;
    rloA[idx] = 0;
}

// ---------------- kernel 3: one full Euler step (GEMM + reduce + phi) -------
// Grid: 96 WGs (i-tile of 16) x 1024 threads (16 waves).
// Wave w: MFMA over k-slice [w*96, w*96+96) for all 96 batches x 16 i.
// LDS tree-reduce 16 partial C-tiles -> phi + Euler update -> write next
// rate planes (double-buffered in/out to avoid cross-WG races).

__global__ __launch_bounds__(NTHR) void k_step(
        const ushort* __restrict__ Whi, const ushort* __restrict__ Wlo,
        const ushort* __restrict__ W2hi, const ushort* __restrict__ W2lo,
        const ushort* __restrict__ rin_hi, const ushort* __restrict__ rin_lo,
        ushort* __restrict__ rout_hi, ushort* __restrict__ rout_lo,
        float* __restrict__ rate, const float* __restrict__ mean,
        float* __restrict__ out, int last)
{
    extern __shared__ float sm[];
    const int tid  = threadIdx.x;
    const int wave = tid >> 6;
    const int lane = tid & 63;
    const int lr   = lane & 15;
    const int lq   = lane >> 4;
    const int it   = blockIdx.x;
    const int i0   = it * 16;
    const int kb   = wave * KSL;

    f32x4 acc1[6], acc2[6];
#pragma unroll
    for (int m = 0; m < 6; m++) {
        acc1[m] = (f32x4){0.0f, 0.0f, 0.0f, 0.0f};
        acc2[m] = (f32x4){0.0f, 0.0f, 0.0f, 0.0f};
    }

    const size_t bof = (size_t)(i0 + lr) * NPAD + kb + lq * 8;
#pragma unroll
    for (int kk = 0; kk < 3; kk++) {
        const int ko = kk * 32;
        short8b bh  = *(const short8b*)(Whi  + bof + ko);
        short8b bl  = *(const short8b*)(Wlo  + bof + ko);
        short8b b2h = *(const short8b*)(W2hi + bof + ko);
        short8b b2l = *(const short8b*)(W2lo + bof + ko);
#pragma unroll
        for (int m = 0; m < 6; m++) {
            const size_t aof = (size_t)(m * 16 + lr) * NPAD + kb + lq * 8 + ko;
            short8b ah = *(const short8b*)(rin_hi + aof);
            short8b al = *(const short8b*)(rin_lo + aof);
            // 3-pass bf16 split (al*bl term ~2^-18 relative: negligible)
            acc1[m] = __builtin_amdgcn_mfma_f32_16x16x32_bf16(ah, bh,  acc1[m], 0, 0, 0);
            acc1[m] = __builtin_amdgcn_mfma_f32_16x16x32_bf16(ah, bl,  acc1[m], 0, 0, 0);
            acc1[m] = __builtin_amdgcn_mfma_f32_16x16x32_bf16(al, bh,  acc1[m], 0, 0, 0);
            acc2[m] = __builtin_amdgcn_mfma_f32_16x16x32_bf16(ah, b2h, acc2[m], 0, 0, 0);
            acc2[m] = __builtin_amdgcn_mfma_f32_16x16x32_bf16(ah, b2l, acc2[m], 0, 0, 0);
            acc2[m] = __builtin_amdgcn_mfma_f32_16x16x32_bf16(al, b2h, acc2[m], 0, 0, 0);
        }
    }

    // ---- LDS tree reduction across 16 waves --------------------------------
    // slot layout: [o(2)][i(16, =lr)][b(100 pad, =16m+4lq+r)] f32; 16B-aligned
    // f32x4 stores; bank spread: lr stride 100 -> 4*lr mod 32, 2-way max.
    const int tbase = lr * BPAD + 4 * lq;

#define WRITE_T(s) { float* p1 = sm + (s) * SLOTF + tbase; float* p2 = p1 + 16 * BPAD; \
    _Pragma("unroll") for (int m = 0; m < 6; m++) { \
        *(f32x4*)(p1 + 16 * m) = acc1[m]; *(f32x4*)(p2 + 16 * m) = acc2[m]; } }

#define ADD_T(s) { const float* p1 = sm + (s) * SLOTF + tbase; const float* p2 = p1 + 16 * BPAD; \
    _Pragma("unroll") for (int m = 0; m < 6; m++) { \
        acc1[m] += *(const f32x4*)(p1 + 16 * m); acc2[m] += *(const f32x4*)(p2 + 16 * m); } }

    if (wave >= 8) WRITE_T(wave - 8);
    __syncthreads();
    if (wave < 8) ADD_T(wave);
    __syncthreads();
    if (wave >= 4 && wave < 8) WRITE_T(wave - 4);
    __syncthreads();
    if (wave < 4) ADD_T(wave);
    __syncthreads();
    if (wave == 2 || wave == 3) WRITE_T(wave - 2);
    __syncthreads();
    if (wave < 2) ADD_T(wave);
    __syncthreads();
    if (wave == 1) WRITE_T(0);
    __syncthreads();
    if (wave == 0) { ADD_T(0); WRITE_T(0); }
    __syncthreads();

    // ---- phi + Euler update for this WG's 96b x 16i block ------------------
    for (int e = tid; e < BATCH * 16; e += NTHR) {
        const int il = e & 15;
        const int b  = e >> 4;
        const int ig = i0 + il;
        const size_t gx = (size_t)b * NPAD + ig;
        float rn = 0.0f;
        if (ig < NN) {
            float u1 = sm[il * BPAD + b];
            float u2 = sm[16 * BPAD + il * BPAD + b];
            float mu = 0.01f * u1 + mean[gx];
            float sg = sqrtf(0.01f * u2 + 25.0f);      // SIG_EXT^2 = 25
            float tr = (ig < NEE) ? 0.005f : 0.001f;
            float Ti = (ig < NEE) ? 100.0f : 200.0f;
            float rr = rate[gx];
            float ph = phi_lif(mu, sg, 0.01f, tr);
            rn = rr + 1e-3f * Ti * (ph - rr);
            rate[gx] = rn;
            if (last) out[(size_t)ig * BATCH + b] = rn;
        }
        ushort h = bf16_rn(rn);
        rout_hi[gx] = h;
        rout_lo[gx] = bf16_rn(rn - bf16f(h));
    }
}

// ---------------- launch ----------------------------------------------------

extern "C" void kernel_launch(void* const* d_in, const int* in_sizes, int n_in,
                              void* d_out, int out_size, void* d_ws, size_t ws_size,
                              hipStream_t stream) {
    const float* hyp      = (const float*)d_in[0];   // [3][4]
    const float* rand_mat = (const float*)d_in[1];   // [1500][1500]
    float* out            = (float*)d_out;           // [1500][8][12]

    char* p = (char*)d_ws;
    ushort* Whi  = (ushort*)p; p += (size_t)NPAD * NPAD * 2;
    ushort* Wlo  = (ushort*)p; p += (size_t)NPAD * NPAD * 2;
    ushort* W2hi = (ushort*)p; p += (size_t)NPAD * NPAD * 2;
    ushort* W2lo = (ushort*)p; p += (size_t)NPAD * NPAD * 2;
    ushort* rhiA = (ushort*)p; p += (size_t)BATCH * NPAD * 2;
    ushort* rloA = (ushort*)p; p += (size_t)BATCH * NPAD * 2;
    ushort* rhiB = (ushort*)p; p += (size_t)BATCH * NPAD * 2;
    ushort* rloB = (ushort*)p; p += (size_t)BATCH * NPAD * 2;
    float*  mean = (float*)p;  p += (size_t)BATCH * NPAD * 4;
    float*  rate = (float*)p;  p += (size_t)BATCH * NPAD * 4;

    hipFuncSetAttribute((const void*)k_step,
                        hipFuncAttributeMaxDynamicSharedMemorySize, SMEM_BYTES);

    k_weights<<<dim3(NPAD / 256, NPAD), 256, 0, stream>>>(hyp, rand_mat, Whi, Wlo, W2hi, W2lo);
    k_init<<<dim3(NPAD / 256, BATCH), 256, 0, stream>>>(mean, rate, rhiA, rloA);

    for (int s = 0; s < NSTEP; s++) {
        const ushort* ih = (s & 1) ? rhiB : rhiA;
        const ushort* il = (s & 1) ? rloB : rloA;
        ushort* oh = (s & 1) ? rhiA : rhiB;
        ushort* ol = (s & 1) ? rloA : rloB;
        k_step<<<dim3(NPAD / 16), dim3(NTHR), SMEM_BYTES, stream>>>(
            Whi, Wlo, W2hi, W2lo, ih, il, oh, ol, rate, mean, out,
            (s == NSTEP - 1) ? 1 : 0);
    }
}

// Round 5
// 1283.079 us; speedup vs baseline: 8.7694x; 1.3462x over previous
//
#include <hip/hip_runtime.h>
#include <hip/hip_bf16.h>
#include <math.h>

// Problem constants
#define NN      1500
#define NEE     1200
#define NPAD    1536
#define BATCH   96
#define NSTEP   60
#define PI_F    3.14159265358979323846f

// k_step geometry: 192 WGs = 96 i-tiles (16) x 2 batch-halves (48)
#define NTHR    512            // 8 waves
#define WAVES   8
#define KSLW    (NPAD / WAVES) // 192 = 6 MFMA k-steps of 32
#define BH      48             // batch-half size
#define MFR     3              // m fragments per wave (48 / 16)

// LDS reduce: 8 slots x [2 outs][16 i][49 pad-b] f32
#define BP      49
#define SLOTF   (2 * 16 * BP)  // 1568 floats
// total: 8 * 1568 * 4 = 50176 B static LDS

typedef __attribute__((ext_vector_type(8))) short short8b;  // 8 bf16
typedef __attribute__((ext_vector_type(4))) float f32x4;    // MFMA acc

// ---------------- bf16 split helpers ----------------------------------------

__device__ __forceinline__ ushort bf16_rn(float x) {
    unsigned u = __float_as_uint(x);
    unsigned r = (u + 0x7FFFu + ((u >> 16) & 1u)) >> 16;
    return (ushort)r;
}
__device__ __forceinline__ float bf16f(ushort h) {
    return __uint_as_float(((unsigned)h) << 16);
}

// ---------------- phi (Ricciardi LIF transfer) ------------------------------

__device__ __forceinline__ float f_ricci(float x) {
    float z = x / (1.0f + x);
    float t = -z;
    float p = 0.14805913578876898f;
    p = p * t + 0.64290613877355551f;
    p = p * t + 1.0616084849547165f;
    p = p * t + 0.93524391761244940f;
    p = p * t + 0.62718906618071668f;
    p = p * t + 0.32171431660633076f;
    p = p * t + 0.32056016125642045f;
    p = p * t + 0.77373949685442023f;
    p = p * t + 0.22757881388024176f;
    p = p * t;
    return logf(2.0f * x + 1.0f) + p;
}

__device__ __forceinline__ float g_ricci(float x) {
    float z = x / (2.0f + x);
    float num = z * (3.5441754117462949f + z * (-7.0529131065835378f + z * (-56.532378057580381f
        + z * (279.56761105465944f + z * (-520.37554849441472f + z * (456.58245777026514f
        + z * (-155.73340457809226f)))))));
    float den = 1.0f + z * (-4.1357968834226053f + z * (-7.2984226138266743f + z * (98.656602235468327f
        + z * (-334.20436223415163f + z * (601.08633903294185f + z * (-599.58577549598340f
        + z * (277.18420330693891f + z * (-16.445022798669722f))))))));
    return num / den;
}

__device__ __forceinline__ float phi_lif(float mu, float sig, float tau, float tau_ref) {
    float xp = mu / sig;
    float xm = (mu - 20.0f) / sig;
    float r0;
    if (xm > 0.0f) {
        r0 = 1.0f / (f_ricci(xp) - f_ricci(xm));
    } else if (xp > 0.0f) {
        r0 = 1.0f / (f_ricci(xp) + expf(xm * xm) * g_ricci(-xm));
    } else {
        float a = g_ricci(-xm) - expf(xp * xp - xm * xm) * g_ricci(-xp);
        r0 = expf(-xm * xm - logf(a));
    }
    r0 = fmaxf(r0, 1e-30f);
    return 1.0f / (tau_ref + tau / r0);
}

__device__ __forceinline__ float pref_of(int n) {
    const float stepE = 179.99f / 1200.0f;
    const float stepI = 179.99f / 300.0f;
    return (n < NEE) ? (float)n * stepE : (float)(n - NEE) * stepI;
}

// ---------------- kernel 1: build bf16-split weight planes [i][k] -----------

__global__ __launch_bounds__(256) void k_weights(const float* __restrict__ hyp,
        const float* __restrict__ rand_mat,
        ushort* __restrict__ Whi, ushort* __restrict__ Wlo,
        ushort* __restrict__ W2hi, ushort* __restrict__ W2lo) {
    int k = blockIdx.x * 256 + threadIdx.x;   // source neuron (contiguous)
    int i = blockIdx.y;                        // dest neuron
    size_t idx = (size_t)i * NPAD + k;
    if (i >= NN || k >= NN) {
        Whi[idx] = 0; Wlo[idx] = 0; W2hi[idx] = 0; W2lo[idx] = 0;
        return;
    }
    float diff = fabsf(pref_of(i) - pref_of(k));
    int conn = (i >= NEE ? 1 : 0) + 2 * (k >= NEE ? 1 : 0);
    float J  = hyp[conn];
    float P  = hyp[4 + conn];
    float Wp = hyp[8 + conn];
    float dn = 4.0f * (PI_F / 180.0f * Wp) * (PI_F / 180.0f * Wp);
    float z = expf((cosf(2.0f * PI_F / 180.0f * diff) - 1.0f) / dn);
    float x = 32.0f * (P * z - rand_mat[(size_t)i * NN + k]);
    float w = J / (1.0f + expf(-x));
    float w2 = w * w;
    ushort h = bf16_rn(w);
    Whi[idx] = h;  Wlo[idx] = bf16_rn(w - bf16f(h));
    ushort h2 = bf16_rn(w2);
    W2hi[idx] = h2; W2lo[idx] = bf16_rn(w2 - bf16f(h2));
}

// ---------------- kernel 2: mean + zero-init rate state ---------------------

__global__ __launch_bounds__(256) void k_init(float* __restrict__ mean,
                                              float* __restrict__ rate,
                                              ushort* __restrict__ rhiA,
                                              ushort* __restrict__ rloA) {
    int i = blockIdx.x * 256 + threadIdx.x;
    int b = blockIdx.y;                        // batch = c*12 + o
    int c = b / 12, o = b % 12;
    const float contrasts[8] = {0.0f, 0.0432773f, 0.103411f, 0.186966f,
                                0.303066f, 0.464386f, 0.68854f, 1.0f};
    float m = 0.0f;
    if (i < NN) {
        float dth = 15.0f * (float)o - pref_of(i);
        const float dn = 4.0f * (PI_F / 180.0f * 30.0f) * (PI_F / 180.0f * 30.0f);
        m = contrasts[c] * 20.0f * expf((cosf(2.0f * PI_F / 180.0f * dth) - 1.0f) / dn);
    }
    size_t idx = (size_t)b * NPAD + i;
    mean[idx] = m;
    rate[idx] = 0.0f;
    rhiA[idx] = 0;
    rloA[idx] = 0;
}

// ---------------- kernel 3: one full Euler step (fused, no global partials) -
// Grid: 192 WGs = (96 i-tiles of 16) x (2 batch-halves of 48); 512 thr (8 waves).
// Wave w handles k-slice [w*192, w*192+192) for the WG's 48b x 16i block.
// 8 waves dump accs to 8 LDS slots -> ONE barrier -> threads sum 8 slots,
// phi + Euler, write next bf16 rate planes (double-buffered).

__global__ __launch_bounds__(NTHR) void k_step(
        const ushort* __restrict__ Whi, const ushort* __restrict__ Wlo,
        const ushort* __restrict__ W2hi, const ushort* __restrict__ W2lo,
        const ushort* __restrict__ rin_hi, const ushort* __restrict__ rin_lo,
        ushort* __restrict__ rout_hi, ushort* __restrict__ rout_lo,
        float* __restrict__ rate, const float* __restrict__ mean,
        float* __restrict__ out, int last)
{
    __shared__ float sm[WAVES * SLOTF];
    const int tid  = threadIdx.x;
    const int wave = tid >> 6;
    const int lane = tid & 63;
    const int lr   = lane & 15;
    const int lq   = lane >> 4;
    const int bx   = blockIdx.x;
    const int it   = bx % 96;          // i-tile; pair (it, it+96-block) shares XCD
    const int bhf  = bx / 96;          // batch half
    const int i0   = it * 16;
    const int b0   = bhf * BH;
    const int kb   = wave * KSLW;

    f32x4 acc1[MFR], acc2[MFR];
#pragma unroll
    for (int m = 0; m < MFR; m++) {
        acc1[m] = (f32x4){0.0f, 0.0f, 0.0f, 0.0f};
        acc2[m] = (f32x4){0.0f, 0.0f, 0.0f, 0.0f};
    }

    const size_t bof = (size_t)(i0 + lr) * NPAD + kb + lq * 8;
#pragma unroll 2
    for (int kk = 0; kk < KSLW / 32; kk++) {
        const int ko = kk * 32;
        short8b wh  = *(const short8b*)(Whi  + bof + ko);
        short8b wl  = *(const short8b*)(Wlo  + bof + ko);
        short8b w2h = *(const short8b*)(W2hi + bof + ko);
        short8b w2l = *(const short8b*)(W2lo + bof + ko);
#pragma unroll
        for (int m = 0; m < MFR; m++) {
            const size_t aof = (size_t)(b0 + m * 16 + lr) * NPAD + kb + lq * 8 + ko;
            short8b ah = *(const short8b*)(rin_hi + aof);
            short8b al = *(const short8b*)(rin_lo + aof);
            // identical pass set to round 4 (numerics held constant)
            acc1[m] = __builtin_amdgcn_mfma_f32_16x16x32_bf16(ah, wh,  acc1[m], 0, 0, 0);
            acc1[m] = __builtin_amdgcn_mfma_f32_16x16x32_bf16(ah, wl,  acc1[m], 0, 0, 0);
            acc1[m] = __builtin_amdgcn_mfma_f32_16x16x32_bf16(al, wh,  acc1[m], 0, 0, 0);
            acc2[m] = __builtin_amdgcn_mfma_f32_16x16x32_bf16(ah, w2h, acc2[m], 0, 0, 0);
            acc2[m] = __builtin_amdgcn_mfma_f32_16x16x32_bf16(ah, w2l, acc2[m], 0, 0, 0);
            acc2[m] = __builtin_amdgcn_mfma_f32_16x16x32_bf16(al, w2h, acc2[m], 0, 0, 0);
        }
    }

    // ---- dump accs to own slot; layout [o][i=lr][b padded BP] ---------------
    // C/D mapping: col(i) = lr, row(b within m-frag) = 4*lq + r
    {
        float* sp = sm + wave * SLOTF;
#pragma unroll
        for (int m = 0; m < MFR; m++) {
            float* p1 = sp + lr * BP + m * 16 + 4 * lq;
            float* p2 = p1 + 16 * BP;
            *(f32x4*)p1 = acc1[m];
            *(f32x4*)p2 = acc2[m];
        }
    }
    __syncthreads();

    // ---- sum 8 slots + phi + Euler update for 48b x 16i block ---------------
    for (int e = tid; e < BH * 16; e += NTHR) {
        const int c = e & 15;          // i within tile
        const int b = e >> 4;          // b within half
        const int ig = i0 + c;
        const int gb = b0 + b;
        const size_t gx = (size_t)gb * NPAD + ig;
        float rn = 0.0f;
        if (ig < NN) {
            float u1 = 0.0f, u2 = 0.0f;
#pragma unroll
            for (int s = 0; s < WAVES; s++) {
                u1 += sm[s * SLOTF + c * BP + b];
                u2 += sm[s * SLOTF + (16 + c) * BP + b];
            }
            float mu = 0.01f * u1 + mean[gx];
            float sg = sqrtf(0.01f * u2 + 25.0f);      // SIG_EXT^2 = 25
            float tr = (ig < NEE) ? 0.005f : 0.001f;
            float Ti = (ig < NEE) ? 100.0f : 200.0f;
            float rr = rate[gx];
            float ph = phi_lif(mu, sg, 0.01f, tr);
            rn = rr + 1e-3f * Ti * (ph - rr);
            rate[gx] = rn;
            if (last) out[(size_t)ig * BATCH + gb] = rn;
        }
        ushort h = bf16_rn(rn);
        rout_hi[gx] = h;
        rout_lo[gx] = bf16_rn(rn - bf16f(h));
    }
}

// ---------------- launch ----------------------------------------------------

extern "C" void kernel_launch(void* const* d_in, const int* in_sizes, int n_in,
                              void* d_out, int out_size, void* d_ws, size_t ws_size,
                              hipStream_t stream) {
    const float* hyp      = (const float*)d_in[0];   // [3][4]
    const float* rand_mat = (const float*)d_in[1];   // [1500][1500]
    float* out            = (float*)d_out;           // [1500][8][12]

    char* p = (char*)d_ws;
    ushort* Whi  = (ushort*)p; p += (size_t)NPAD * NPAD * 2;
    ushort* Wlo  = (ushort*)p; p += (size_t)NPAD * NPAD * 2;
    ushort* W2hi = (ushort*)p; p += (size_t)NPAD * NPAD * 2;
    ushort* W2lo = (ushort*)p; p += (size_t)NPAD * NPAD * 2;
    ushort* rhiA = (ushort*)p; p += (size_t)BATCH * NPAD * 2;
    ushort* rloA = (ushort*)p; p += (size_t)BATCH * NPAD * 2;
    ushort* rhiB = (ushort*)p; p += (size_t)BATCH * NPAD * 2;
    ushort* rloB = (ushort*)p; p += (size_t)BATCH * NPAD * 2;
    float*  mean = (float*)p;  p += (size_t)BATCH * NPAD * 4;
    float*  rate = (float*)p;  p += (size_t)BATCH * NPAD * 4;

    k_weights<<<dim3(NPAD / 256, NPAD), 256, 0, stream>>>(hyp, rand_mat, Whi, Wlo, W2hi, W2lo);
    k_init<<<dim3(NPAD / 256, BATCH), 256, 0, stream>>>(mean, rate, rhiA, rloA);

    for (int s = 0; s < NSTEP; s++) {
        const ushort* ih = (s & 1) ? rhiB : rhiA;
        const ushort* il = (s & 1) ? rloB : rloA;
        ushort* oh = (s & 1) ? rhiA : rhiB;
        ushort* ol = (s & 1) ? rloA : rloB;
        k_step<<<dim3(192), dim3(NTHR), 0, stream>>>(
            Whi, Wlo, W2hi, W2lo, ih, il, oh, ol, rate, mean, out,
            (s == NSTEP - 1) ? 1 : 0);
    }
}